// Round 5
// baseline (576.308 us; speedup 1.0000x reference)
//
#include <hip/hip_runtime.h>

typedef unsigned short ushort_t;
typedef __attribute__((ext_vector_type(8))) short bf16x8;   // 8 bf16 in 4 VGPRs
typedef __attribute__((ext_vector_type(4))) float f32x4;

#define H 512
#define E 1024
#define S 2048
#define B 32

__device__ __forceinline__ ushort_t f2bf(float f) {
    unsigned u = __float_as_uint(f);
    unsigned r = (u + 0x7FFFu + ((u >> 16) & 1u)) >> 16;   // RNE
    return (ushort_t)r;
}

// round-half-up bf16 pack of two floats: low = bf(x), high = bf(y). 3 VALU ops.
__device__ __forceinline__ unsigned pkbf(float x, float y) {
    unsigned u0 = __float_as_uint(x) + 0x8000u;
    unsigned u1 = __float_as_uint(y) + 0x8000u;
    return __builtin_amdgcn_perm(u1, u0, 0x07060302u);
}

__device__ __forceinline__ uint4 pk8(float4 a, float4 b) {
    uint4 u;
    u.x = pkbf(a.x, a.y); u.y = pkbf(a.z, a.w);
    u.z = pkbf(b.x, b.y); u.w = pkbf(b.z, b.w);
    return u;
}

// padded LDS slot addressing: 16B slots, +16B pad every 16 slots (breaks 256B-stride conflicts)
__device__ __forceinline__ int boff(int slot) { return (slot << 4) + ((slot >> 4) << 4); }

// hb[b][n] = hidden[b] @ Wh[:,n] + ba[n]   — 32 blocks x 512 thr, no atomics
__global__ void prep_hb(const float* __restrict__ hidden, const float* __restrict__ Wa,
                        const float* __restrict__ ba, float* __restrict__ hb) {
    int b = blockIdx.x, n = threadIdx.x;
    __shared__ float hs[H];
    hs[n] = hidden[b * H + n];
    __syncthreads();
    float a0 = 0.f, a1 = 0.f, a2 = 0.f, a3 = 0.f;
    #pragma unroll 4
    for (int k = 0; k < H; k += 4) {
        a0 += hs[k]     * Wa[(size_t)k * H + n];
        a1 += hs[k + 1] * Wa[(size_t)(k + 1) * H + n];
        a2 += hs[k + 2] * Wa[(size_t)(k + 2) * H + n];
        a3 += hs[k + 3] * Wa[(size_t)(k + 3) * H + n];
    }
    hb[b * H + n] = a0 + a1 + a2 + a3 + ba[n];
}

// Swizzle We (= Wa[512:]) into bf16 MFMA-B-fragment order:
// wef[((kt*32+nt)*64 + lane)*8 + j] = We[kt*32 + (lane>>4)*8 + j][nt*16 + (lane&15)]
__global__ void prep_wef(const float* __restrict__ Wa, ushort_t* __restrict__ wef) {
    int g = blockIdx.x * 256 + threadIdx.x;      // 0..65535
    int kt = g >> 11, nt = (g >> 6) & 31, l = g & 63;
    int kbase = kt * 32 + ((l >> 4) << 3);
    int n = nt * 16 + (l & 15);
    #pragma unroll
    for (int j = 0; j < 8; ++j)
        wef[(size_t)g * 8 + j] = f2bf(Wa[(size_t)(H + kbase + j) * H + n]);
}

// scores[b][s] = v . tanh( enc[b,s,:] @ We + hb[b,:] )
// 512 thr / 8 waves; tile M=128 x N=512, K=1024 in 4 quarters of 256.
// A-tile bf16 resident in LDS (ping-pong 2x68KB, staged through regs while computing);
// B (fragment-ordered wef) streamed from L2 into regs, depth-2 prefetch, NO barriers
// except one per quarter.
__launch_bounds__(512, 2)
__global__ void score_kernel(const float* __restrict__ enc, const ushort_t* __restrict__ wef,
                             const float* __restrict__ hb, const float* __restrict__ v,
                             float* __restrict__ scores) {
    const int tid = threadIdx.x;
    const int wave = tid >> 6, lane = tid & 63;
    const int qq = lane >> 4, nl = lane & 15;
    const int b = blockIdx.y, s0 = blockIdx.x * 128;

    __shared__ char arena[2 * 69632];     // two A-quarter buffers (4096 slots + pads each)
    __shared__ float sred[8 * 128];

    f32x4 acc[8][4] = {};                 // [mt][ntl]

    // ---- A staging mapping: thread handles row sr, chunk set c2 ----
    const int sr = tid >> 2;              // 0..127
    const int c2 = tid & 3;
    const float* ap = enc + ((size_t)b * S + s0 + sr) * E;
    const int wbase = (sr >> 4) * 64 + (sr & 15) + 16 * c2;   // mt*64 + lane_frag

    // ---- B stream base: wave owns nt = wave*4 + ntl ----
    const ushort_t* wb = wef + (size_t)(wave * 4) * 512 + lane * 8;

    // ---- prologue: stage quarter 0 into buffer 0 (two batches of 4 iters) ----
    #pragma unroll
    for (int h = 0; h < 2; ++h) {
        float4 t0[4], t1[4];
        #pragma unroll
        for (int i2 = 0; i2 < 4; ++i2) {
            const float* s = ap + (size_t)((h * 4 + i2) * 4 + c2) * 8;
            t0[i2] = *(const float4*)s;
            t1[i2] = *(const float4*)(s + 4);
        }
        #pragma unroll
        for (int i2 = 0; i2 < 4; ++i2) {
            int i = h * 4 + i2;
            *(uint4*)(arena + boff(i * 512 + wbase)) = pk8(t0[i2], t1[i2]);
        }
    }

    // B prefetch for kt = 0, 1
    bf16x8 bq[2][4];
    #pragma unroll
    for (int ntl = 0; ntl < 4; ++ntl) {
        bq[0][ntl] = *(const bf16x8*)(wb + ntl * 512);
        bq[1][ntl] = *(const bf16x8*)(wb + 16384 + ntl * 512);
    }
    __syncthreads();

    float4 ua[2][2];
    int buf = 0;
    for (int q4 = 0; q4 < 4; ++q4) {
        char* cb = arena + buf * 69632;
        char* nb = arena + (buf ^ 1) * 69632;
        #pragma unroll
        for (int j = 0; j < 8; ++j) {
            const int kt = q4 * 8 + j;
            // local copies so the refill loads can issue before/behind MFMA freely
            bf16x8 bc[4];
            #pragma unroll
            for (int ntl = 0; ntl < 4; ++ntl) bc[ntl] = bq[kt & 1][ntl];
            if (kt < 30) {
                #pragma unroll
                for (int ntl = 0; ntl < 4; ++ntl)
                    bq[kt & 1][ntl] =
                        *(const bf16x8*)(wb + (size_t)(kt + 2) * 16384 + ntl * 512);
            }
            // rolling staging of next quarter: write iter j-2, load iter j
            if (q4 < 3) {
                if (j >= 2)
                    *(uint4*)(nb + boff((j - 2) * 512 + wbase)) =
                        pk8(ua[j & 1][0], ua[j & 1][1]);
                const float* sld = ap + (q4 + 1) * 256 + (size_t)(j * 4 + c2) * 8;
                ua[j & 1][0] = *(const float4*)sld;
                ua[j & 1][1] = *(const float4*)(sld + 4);
            }
            // A fragments from LDS
            bf16x8 afr[8];
            #pragma unroll
            for (int mt = 0; mt < 8; ++mt)
                afr[mt] = *(const bf16x8*)(cb + boff((j * 8 + mt) * 64 + lane));
            // MFMA 8x4
            #pragma unroll
            for (int ntl = 0; ntl < 4; ++ntl)
                #pragma unroll
                for (int mt = 0; mt < 8; ++mt)
                    acc[mt][ntl] = __builtin_amdgcn_mfma_f32_16x16x32_bf16(
                        afr[mt], bc[ntl], acc[mt][ntl], 0, 0, 0);
        }
        if (q4 < 3) {     // tail: staging iters 6,7 of next quarter
            *(uint4*)(nb + boff(6 * 512 + wbase)) = pk8(ua[0][0], ua[0][1]);
            *(uint4*)(nb + boff(7 * 512 + wbase)) = pk8(ua[1][0], ua[1][1]);
        }
        __syncthreads();
        buf ^= 1;
    }

    // ---- epilogue: p[m] = sum_n v[n]*tanh(acc + hb[n]) over wave's 64 cols ----
    float p[32];
    #pragma unroll
    for (int i = 0; i < 32; ++i) p[i] = 0.f;
    #pragma unroll
    for (int ntl = 0; ntl < 4; ++ntl) {
        int n = wave * 64 + ntl * 16 + nl;
        float hv = hb[b * H + n];
        float vv = v[n];
        #pragma unroll
        for (int mt = 0; mt < 8; ++mt)
            #pragma unroll
            for (int rr = 0; rr < 4; ++rr) {
                float x = acc[mt][ntl][rr] + hv;
                float t = __expf(2.f * x);            // |x| <~ 6 here: no overflow
                p[mt * 4 + rr] += vv * ((t - 1.f) / (t + 1.f));
            }
    }
    #pragma unroll
    for (int off = 1; off < 16; off <<= 1) {
        #pragma unroll
        for (int i = 0; i < 32; ++i) p[i] += __shfl_xor(p[i], off, 64);
    }
    if (nl == 0) {
        #pragma unroll
        for (int mt = 0; mt < 8; ++mt)
            #pragma unroll
            for (int rr = 0; rr < 4; ++rr)
                sred[wave * 128 + mt * 16 + qq * 4 + rr] = p[mt * 4 + rr];
    }
    __syncthreads();
    if (tid < 128) {
        float s = 0.f;
        #pragma unroll
        for (int w = 0; w < 8; ++w) s += sred[w * 128 + tid];
        scores[(size_t)b * S + s0 + tid] = s;
    }
}

// softmax over S per b; writes attention weights to out[B*E + ...] and zeros context region
__global__ void softmax_kernel(const float* __restrict__ scores, float* __restrict__ out) {
    int b = blockIdx.x, tid = threadIdx.x;
    const float* row = scores + (size_t)b * S;
    float loc[8];
    float mx = -3.4e38f;
    #pragma unroll
    for (int i = 0; i < 8; ++i) { loc[i] = row[tid + i * 256]; mx = fmaxf(mx, loc[i]); }
    #pragma unroll
    for (int off = 32; off > 0; off >>= 1) mx = fmaxf(mx, __shfl_xor(mx, off, 64));
    __shared__ float wm[4], wsm[4];
    if ((tid & 63) == 0) wm[tid >> 6] = mx;
    __syncthreads();
    mx = fmaxf(fmaxf(wm[0], wm[1]), fmaxf(wm[2], wm[3]));
    float sum = 0.f;
    #pragma unroll
    for (int i = 0; i < 8; ++i) { loc[i] = __expf(loc[i] - mx); sum += loc[i]; }
    #pragma unroll
    for (int off = 32; off > 0; off >>= 1) sum += __shfl_xor(sum, off, 64);
    if ((tid & 63) == 0) wsm[tid >> 6] = sum;
    __syncthreads();
    sum = wsm[0] + wsm[1] + wsm[2] + wsm[3];
    float inv = 1.f / sum;
    #pragma unroll
    for (int i = 0; i < 8; ++i) out[B * E + (size_t)b * S + tid + i * 256] = loc[i] * inv;
    #pragma unroll
    for (int i = 0; i < 4; ++i) out[(size_t)b * E + tid + i * 256] = 0.f;   // zero context for atomics
}

// context[b][e] = sum_s w[b][s] * enc[b][s][e]; 64 s-rows per block, float4/thread
__global__ void context_kernel(const float* __restrict__ enc, const float* __restrict__ w_attn,
                               float* __restrict__ out_ctx) {
    int sc = blockIdx.x, b = blockIdx.y;
    int e = threadIdx.x * 4;
    const float* w  = w_attn + (size_t)b * S + sc * 64;
    const float* ep = enc + ((size_t)b * S + sc * 64) * E + e;
    float a0 = 0.f, a1 = 0.f, a2 = 0.f, a3 = 0.f;
    #pragma unroll 16
    for (int s = 0; s < 64; ++s) {
        float ws = w[s];
        float4 x = *(const float4*)(ep + (size_t)s * E);
        a0 += ws * x.x; a1 += ws * x.y; a2 += ws * x.z; a3 += ws * x.w;
    }
    float* dst = &out_ctx[(size_t)b * E + e];
    atomicAdd(dst + 0, a0);
    atomicAdd(dst + 1, a1);
    atomicAdd(dst + 2, a2);
    atomicAdd(dst + 3, a3);
}

extern "C" void kernel_launch(void* const* d_in, const int* in_sizes, int n_in,
                              void* d_out, int out_size, void* d_ws, size_t ws_size,
                              hipStream_t stream) {
    const float* hidden = (const float*)d_in[0];
    const float* enc    = (const float*)d_in[1];
    const float* Wa     = (const float*)d_in[2];
    const float* ba     = (const float*)d_in[3];
    const float* v      = (const float*)d_in[4];
    float* out = (float*)d_out;

    char* ws = (char*)d_ws;
    ushort_t* wef = (ushort_t*)ws;                        // 1 MiB  (bf16 We fragments)
    float* hb     = (float*)(ws + (1 << 20));             // 64 KiB
    float* scores = (float*)(ws + (1 << 20) + (1 << 16)); // 256 KiB

    prep_hb<<<B, 512, 0, stream>>>(hidden, Wa, ba, hb);
    prep_wef<<<256, 256, 0, stream>>>(Wa, wef);
    score_kernel<<<dim3(S / 128, B), 512, 0, stream>>>(enc, wef, hb, v, scores);
    softmax_kernel<<<B, 256, 0, stream>>>(scores, out);
    context_kernel<<<dim3(32, B), 256, 0, stream>>>(enc, out + B * E, out);
}